// Round 11
// baseline (43.239 us; speedup 1.0000x reference)
//
#include <hip/hip_runtime.h>
#include <hip/hip_bf16.h>

constexpr int HIDDEN = 256;
constexpr int BAG    = 32;
constexpr int FEAT   = 41025;   // FEATURE_COUNT + 1 (includes zero pad row)
constexpr int NJ     = 64;      // P columns: [0:32]=us-proj, [32:64]=them-proj
constexpr int NTILES = (FEAT + 63) / 64;   // 642

using bf16x8 = __attribute__((ext_vector_type(8))) short;
using f32x4  = __attribute__((ext_vector_type(4))) float;

__device__ inline short f2bf(float f) {            // fp32 -> bf16 RNE
    __hip_bfloat16 h = __float2bfloat16(f);        // pairs fuse to v_cvt_pk_bf16_f32
    return __builtin_bit_cast(short, h);
}
__device__ inline bf16x8 pack8(float4 a, float4 b) {
    bf16x8 r;
    r[0]=f2bf(a.x); r[1]=f2bf(a.y); r[2]=f2bf(a.z); r[3]=f2bf(a.w);
    r[4]=f2bf(b.x); r[5]=f2bf(b.y); r[6]=f2bf(b.z); r[7]=f2bf(b.w);
    return r;
}

// ---------- k0: P(bf16) = emb @ W2d via MFMA, REGISTERS ONLY (no LDS, no barriers)
// A-frag row is per-lane (row = ml), so each lane loads its own emb row slice
// directly: per kt the wave covers 16 full 128-B lines exactly once.
// B (fc1_w as W2d, 64 KB) is streamed per kt from L2 (hot across all blocks).
__global__ __launch_bounds__(256) void k0_project_mfma(
    const float*    __restrict__ emb,
    const float*    __restrict__ fc1_w,
    unsigned short* __restrict__ P)     // bf16 [FEAT][NJ]
{
    const int tid  = threadIdx.x;
    const int lane = tid & 63, wave = tid >> 6;
    const int g = lane >> 4, ml = lane & 15;
    const int rbase = blockIdx.x * 64 + wave * 16;     // wave's 16 rows

    int fr = rbase + ml; if (fr >= FEAT) fr = FEAT - 1;   // clamp (stores guarded)
    const float* ap = emb + (size_t)fr * 256 + g * 8;     // lane's row, k-base g*8

    // ---- prefetch ALL A fragments: 8 kt x 32 B, fully independent loads
    float4 a0[8], a1[8];
#pragma unroll
    for (int kt = 0; kt < 8; ++kt) {
        a0[kt] = *reinterpret_cast<const float4*>(ap + kt * 32);
        a1[kt] = *reinterpret_cast<const float4*>(ap + kt * 32 + 4);
    }

    // ---- B base pointer for this lane: W2d col j = fc1_w[j&31][(j>>5)*256 + k]
    const float* bp[4];
#pragma unroll
    for (int nt = 0; nt < 4; ++nt) {
        const int j = nt * 16 + ml;
        bp[nt] = fc1_w + (size_t)(j & 31) * 512 + ((j >> 5) << 8) + g * 8;
    }

    f32x4 acc[4] = {{0.f,0.f,0.f,0.f},{0.f,0.f,0.f,0.f},
                    {0.f,0.f,0.f,0.f},{0.f,0.f,0.f,0.f}};
#pragma unroll
    for (int kt = 0; kt < 8; ++kt) {
        const bf16x8 af = pack8(a0[kt], a1[kt]);
#pragma unroll
        for (int nt = 0; nt < 4; ++nt) {
            const float4 b0 = *reinterpret_cast<const float4*>(bp[nt] + kt * 32);
            const float4 b1 = *reinterpret_cast<const float4*>(bp[nt] + kt * 32 + 4);
            acc[nt] = __builtin_amdgcn_mfma_f32_16x16x32_bf16(af, pack8(b0, b1),
                                                              acc[nt], 0, 0, 0);
        }
    }

    // ---- store bf16 P. D layout: row = g*4 + r, col = ml
#pragma unroll
    for (int nt = 0; nt < 4; ++nt) {
#pragma unroll
        for (int r = 0; r < 4; ++r) {
            const int f = rbase + g * 4 + r;
            if (f < FEAT)
                P[(size_t)f * NJ + nt * 16 + ml] =
                    (unsigned short)f2bf(acc[nt][r]);
        }
    }
}

// ---------- k1: gather bf16 P rows (64 B per half) + fused MLP. One wave/row.
__global__ __launch_bounds__(256) void k1_gather_mlp(
    const int*            __restrict__ us,
    const int*            __restrict__ them,
    const unsigned short* __restrict__ P,     // bf16 [FEAT][NJ]
    const float* __restrict__ b1,
    const float* __restrict__ w2, const float* __restrict__ b2,
    const float* __restrict__ w3, const float* __restrict__ b3,
    float*       __restrict__ out)
{
    __shared__ float w2_lds[32][33];
    __shared__ float y1_lds[4][32];

    const int tid  = threadIdx.x;
    const int wave = tid >> 6;
    const int lane = tid & 63;

    for (int k = tid; k < 32 * 32; k += 256)
        w2_lds[k >> 5][k & 31] = w2[k];
    __syncthreads();

    const int row = blockIdx.x * 4 + wave;
    int idx;
    {
        const int* up = us   + (size_t)row * BAG;
        const int* tp = them + (size_t)row * BAG;
        idx = (lane < BAG) ? up[lane] : tp[lane - BAG];
    }

    // lane j<32: us-part col j; lane 32+j: them-part col 32+j
    float acc = 0.f;
    const int srcbase = lane & 32;
#pragma unroll
    for (int i = 0; i < BAG; ++i) {
        const int f = __shfl(idx, srcbase + i);
        const unsigned short pv = P[(size_t)f * NJ + lane];
        acc += __builtin_bit_cast(float, (unsigned)pv << 16);
    }
    acc += __shfl_xor(acc, 32);

    if (lane < 32)
        y1_lds[wave][lane] = fminf(fmaxf(acc + b1[lane], 0.f), 1.f);
    __syncthreads();

    float r3 = 0.f;
    if (lane < 32) {
        float s = b2[lane];
#pragma unroll
        for (int k = 0; k < 32; ++k) s += y1_lds[wave][k] * w2_lds[lane][k];
        r3 = fminf(fmaxf(s, 0.f), 1.f) * w3[lane];
    }
    r3 += __shfl_xor(r3, 16); r3 += __shfl_xor(r3, 8); r3 += __shfl_xor(r3, 4);
    r3 += __shfl_xor(r3, 2);  r3 += __shfl_xor(r3, 1);
    if (lane == 0) out[row] = tanhf(r3 + b3[0]);
}

// ---------- fallback: R0 monolithic kernel (if ws too small) ----------
__global__ __launch_bounds__(256) void nnue_fused(
    const int*   __restrict__ us,
    const int*   __restrict__ them,
    const float* __restrict__ emb,
    const float* __restrict__ w1, const float* __restrict__ b1,
    const float* __restrict__ w2, const float* __restrict__ b2,
    const float* __restrict__ w3, const float* __restrict__ b3,
    float*       __restrict__ out)
{
    __shared__ float x_lds[4][2 * HIDDEN];
    __shared__ float y1_lds[4][32];
    __shared__ float y2_lds[4][32];

    const int tid  = threadIdx.x;
    const int wave = tid >> 6;
    const int lane = tid & 63;
    const int row  = blockIdx.x * 4 + wave;

    int myidx;
    {
        const int* up = us   + (size_t)row * BAG;
        const int* tp = them + (size_t)row * BAG;
        myidx = (lane < BAG) ? up[lane] : tp[lane - BAG];
    }
    const float4* emb4 = reinterpret_cast<const float4*>(emb);
    float4 accU = make_float4(0.f, 0.f, 0.f, 0.f);
    float4 accT = make_float4(0.f, 0.f, 0.f, 0.f);
#pragma unroll
    for (int i = 0; i < BAG; ++i) {
        const int iu = __shfl(myidx, i);
        const int it = __shfl(myidx, BAG + i);
        const float4 vu = emb4[(size_t)iu * (HIDDEN / 4) + lane];
        const float4 vt = emb4[(size_t)it * (HIDDEN / 4) + lane];
        accU.x += vu.x; accU.y += vu.y; accU.z += vu.z; accU.w += vu.w;
        accT.x += vt.x; accT.y += vt.y; accT.z += vt.z; accT.w += vt.w;
    }
    {
        float4* xv = reinterpret_cast<float4*>(&x_lds[wave][0]);
        xv[lane]      = accU;
        xv[64 + lane] = accT;
    }
    __syncthreads();
    {
        const int r    = tid >> 6;
        const int sub  = tid & 63;
        const int j    = sub >> 1;
        const int half = sub & 1;
        const float4* xr = reinterpret_cast<const float4*>(&x_lds[r][0]) + half * 64;
        const float4* wr = reinterpret_cast<const float4*>(w1 + (size_t)j * (2 * HIDDEN)) + half * 64;
        float s = 0.f;
#pragma unroll 8
        for (int k = 0; k < 64; ++k) {
            const float4 xk = xr[k];
            const float4 wk = wr[k];
            s += xk.x * wk.x + xk.y * wk.y + xk.z * wk.z + xk.w * wk.w;
        }
        s += __shfl_xor(s, 1);
        if (half == 0) { s += b1[j]; y1_lds[r][j] = fminf(fmaxf(s, 0.f), 1.f); }
    }
    __syncthreads();
    if (tid < 4 * 32) {
        const int r = tid >> 5;
        const int j = tid & 31;
        const float* wr = w2 + j * 32;
        float s = b2[j];
#pragma unroll
        for (int k = 0; k < 32; ++k) s += y1_lds[r][k] * wr[k];
        y2_lds[r][j] = fminf(fmaxf(s, 0.f), 1.f);
    }
    __syncthreads();
    if (tid < 4) {
        const int r = tid;
        float s = b3[0];
#pragma unroll
        for (int k = 0; k < 32; ++k) s += y2_lds[r][k] * w3[k];
        out[blockIdx.x * 4 + r] = tanhf(s);
    }
}

extern "C" void kernel_launch(void* const* d_in, const int* in_sizes, int n_in,
                              void* d_out, int out_size, void* d_ws, size_t ws_size,
                              hipStream_t stream) {
    const int*   us   = (const int*)  d_in[0];
    const int*   them = (const int*)  d_in[1];
    const float* emb  = (const float*)d_in[2];
    const float* w1   = (const float*)d_in[3];
    const float* b1   = (const float*)d_in[4];
    const float* w2   = (const float*)d_in[5];
    const float* b2   = (const float*)d_in[6];
    const float* w3   = (const float*)d_in[7];
    const float* b3   = (const float*)d_in[8];
    float* out = (float*)d_out;

    const int batch = in_sizes[0] / BAG;                                  // 8192
    const size_t p_bytes = (size_t)FEAT * NJ * sizeof(unsigned short);    // 5.25 MB

    if (ws_size >= p_bytes) {
        unsigned short* P = (unsigned short*)d_ws;
        k0_project_mfma<<<NTILES, 256, 0, stream>>>(emb, w1, P);
        k1_gather_mlp<<<batch / 4, 256, 0, stream>>>(us, them, P,
                                                     b1, w2, b2, w3, b3, out);
    } else {
        nnue_fused<<<(batch + 3) / 4, 256, 0, stream>>>(us, them, emb,
                                                        w1, b1, w2, b2, w3, b3, out);
    }
}

// Round 12
// 32.003 us; speedup vs baseline: 1.3511x; 1.3511x over previous
//
#include <hip/hip_runtime.h>
#include <hip/hip_bf16.h>

constexpr int HIDDEN = 256;
constexpr int BAG    = 32;
constexpr int FEAT   = 41025;   // FEATURE_COUNT + 1 (includes zero pad row)
constexpr int NJ     = 64;      // P columns: [0:32]=us-proj, [32:64]=them-proj
constexpr int NTILES = (FEAT + 63) / 64;   // 642
constexpr int LDSS   = 264;     // ushort stride per LDS A-row (256 + 8 pad)

using bf16x8 = __attribute__((ext_vector_type(8))) short;
using f32x4  = __attribute__((ext_vector_type(4))) float;

__device__ inline short f2bf(float f) {            // fp32 -> bf16 RNE
    __hip_bfloat16 h = __float2bfloat16(f);        // pairs fuse to v_cvt_pk_bf16_f32
    return __builtin_bit_cast(short, h);
}
__device__ inline void cvt_store(unsigned short* dst, float4 v) {
    ushort4 b; b.x = (unsigned short)f2bf(v.x); b.y = (unsigned short)f2bf(v.y);
    b.z = (unsigned short)f2bf(v.z); b.w = (unsigned short)f2bf(v.w);
    *reinterpret_cast<ushort4*>(dst) = b;
}
__device__ inline bf16x8 pack8(float4 a, float4 b) {
    bf16x8 r;
    r[0]=f2bf(a.x); r[1]=f2bf(a.y); r[2]=f2bf(a.z); r[3]=f2bf(a.w);
    r[4]=f2bf(b.x); r[5]=f2bf(b.y); r[6]=f2bf(b.z); r[7]=f2bf(b.w);
    return r;
}

// ---------- k_pre: fc1_w -> Wfrag bf16 fragment layout (32 KB), run once ----------
// frag (nt,kt), lane l=(g,ml): bf16x8 of W2d col j=nt*16+ml, k=kt*32+g*8..+8
// where W2d[j][k] = fc1_w[j&31][(j>>5)*256 + k].  Stored at Wfrag[(nt*8+kt)*64 + l].
__global__ __launch_bounds__(256) void k_pre_wfrag(
    const float* __restrict__ fc1_w,
    int4*        __restrict__ Wfrag)          // 2048 x 16 B
{
    const int tid = threadIdx.x;
#pragma unroll
    for (int s = 0; s < 8; ++s) {
        const int e    = s * 256 + tid;       // frag-lane entry 0..2047
        const int lane = e & 63, fid = e >> 6;
        const int nt = fid >> 3, kt = fid & 7;
        const int g = lane >> 4, ml = lane & 15;
        const int j = nt * 16 + ml;
        const float* src = fc1_w + (size_t)(j & 31) * 512 + ((j >> 5) << 8)
                          + kt * 32 + g * 8;
        const float4 x0 = *reinterpret_cast<const float4*>(src);
        const float4 x1 = *reinterpret_cast<const float4*>(src + 4);
        const bf16x8 fr = pack8(x0, x1);
        Wfrag[e] = __builtin_bit_cast(int4, fr);
    }
}

// ---------- k0: P = emb @ W2d via bf16 MFMA. A staged via reg-split LDS (R8);
// B fragments loaded DIRECT from Wfrag (L2-hot, no LDS bounce, no cvt).
__global__ __launch_bounds__(256, 2) void k0_project_mfma(
    const float* __restrict__ emb,
    const int4*  __restrict__ Wfrag,
    float*       __restrict__ P)
{
    __shared__ unsigned short a_lds[64 * LDSS];   // A: [row][k] bf16, 33 KB

    const int tid = threadIdx.x;
    const int f0  = blockIdx.x * 64;
    const float4* emb4 = reinterpret_cast<const float4*>(emb);

    // ---- phase 1a: issue all 16 A loads (64 rows x 64 float4, coalesced)
    float4 aR[16];
#pragma unroll
    for (int s = 0; s < 16; ++s) {
        const int idx4 = s * 256 + tid;        // 0..4095
        const int row  = idx4 >> 6;
        const int kq4  = idx4 & 63;
        int grow = f0 + row; if (grow >= FEAT) grow = FEAT - 1;   // clamp
        aR[s] = emb4[(size_t)grow * 64 + kq4];
    }
    // ---- phase 1b: B fragments direct to registers (32 x dwordx4, L2-hot)
    const int lane = tid & 63, wave = tid >> 6;
    bf16x8 breg[4][8];
#pragma unroll
    for (int nt = 0; nt < 4; ++nt)
#pragma unroll
        for (int kt = 0; kt < 8; ++kt)
            breg[nt][kt] = __builtin_bit_cast(bf16x8, Wfrag[(nt * 8 + kt) * 64 + lane]);

    // ---- phase 2: convert + LDS write A (drains incrementally via vmcnt)
#pragma unroll
    for (int s = 0; s < 16; ++s) {
        const int idx4 = s * 256 + tid;
        const int row  = idx4 >> 6;
        const int kq4  = idx4 & 63;
        cvt_store(&a_lds[row * LDSS + kq4 * 4], aR[s]);
    }
    __syncthreads();

    const int g = lane >> 4, ml = lane & 15;
    const int mw = wave * 16;                  // wave's 16 rows

    f32x4 acc[4] = {{0.f,0.f,0.f,0.f},{0.f,0.f,0.f,0.f},
                    {0.f,0.f,0.f,0.f},{0.f,0.f,0.f,0.f}};
#pragma unroll
    for (int kt = 0; kt < 8; ++kt) {           // K = 8 x 32; one ds_read_b128/kt
        const bf16x8 af = *reinterpret_cast<const bf16x8*>(
            &a_lds[(mw + ml) * LDSS + kt * 32 + g * 8]);
#pragma unroll
        for (int nt = 0; nt < 4; ++nt)
            acc[nt] = __builtin_amdgcn_mfma_f32_16x16x32_bf16(af, breg[nt][kt],
                                                              acc[nt], 0, 0, 0);
    }

    // D layout: row = g*4 + r, col = ml (verified C/D mapping)
#pragma unroll
    for (int nt = 0; nt < 4; ++nt) {
#pragma unroll
        for (int r = 0; r < 4; ++r) {
            const int f = f0 + mw + g * 4 + r;
            if (f < FEAT)
                P[(size_t)f * NJ + nt * 16 + ml] = acc[nt][r];
        }
    }
}

// ---------- k1: gather P rows (128 B each) + fused MLP. One wave per batch row.
__global__ __launch_bounds__(256) void k1_gather_mlp(
    const int*   __restrict__ us,
    const int*   __restrict__ them,
    const float* __restrict__ P,
    const float* __restrict__ b1,
    const float* __restrict__ w2, const float* __restrict__ b2,
    const float* __restrict__ w3, const float* __restrict__ b3,
    float*       __restrict__ out)
{
    __shared__ float w2_lds[32][33];
    __shared__ float y1_lds[4][32];

    const int tid  = threadIdx.x;
    const int wave = tid >> 6;
    const int lane = tid & 63;

    for (int k = tid; k < 32 * 32; k += 256)
        w2_lds[k >> 5][k & 31] = w2[k];
    __syncthreads();

    const int row = blockIdx.x * 4 + wave;
    int idx;
    {
        const int* up = us   + (size_t)row * BAG;
        const int* tp = them + (size_t)row * BAG;
        idx = (lane < BAG) ? up[lane] : tp[lane - BAG];
    }

    float acc = 0.f;
    const int srcbase = lane & 32;
#pragma unroll
    for (int i = 0; i < BAG; ++i) {
        const int f = __shfl(idx, srcbase + i);
        acc += P[(size_t)f * NJ + lane];
    }
    acc += __shfl_xor(acc, 32);

    if (lane < 32)
        y1_lds[wave][lane] = fminf(fmaxf(acc + b1[lane], 0.f), 1.f);
    __syncthreads();

    float r3 = 0.f;
    if (lane < 32) {
        float s = b2[lane];
#pragma unroll
        for (int k = 0; k < 32; ++k) s += y1_lds[wave][k] * w2_lds[lane][k];
        r3 = fminf(fmaxf(s, 0.f), 1.f) * w3[lane];
    }
    r3 += __shfl_xor(r3, 16); r3 += __shfl_xor(r3, 8); r3 += __shfl_xor(r3, 4);
    r3 += __shfl_xor(r3, 2);  r3 += __shfl_xor(r3, 1);
    if (lane == 0) out[row] = tanhf(r3 + b3[0]);
}

// ---------- fallback: R0 monolithic kernel (if ws too small) ----------
__global__ __launch_bounds__(256) void nnue_fused(
    const int*   __restrict__ us,
    const int*   __restrict__ them,
    const float* __restrict__ emb,
    const float* __restrict__ w1, const float* __restrict__ b1,
    const float* __restrict__ w2, const float* __restrict__ b2,
    const float* __restrict__ w3, const float* __restrict__ b3,
    float*       __restrict__ out)
{
    __shared__ float x_lds[4][2 * HIDDEN];
    __shared__ float y1_lds[4][32];
    __shared__ float y2_lds[4][32];

    const int tid  = threadIdx.x;
    const int wave = tid >> 6;
    const int lane = tid & 63;
    const int row  = blockIdx.x * 4 + wave;

    int myidx;
    {
        const int* up = us   + (size_t)row * BAG;
        const int* tp = them + (size_t)row * BAG;
        myidx = (lane < BAG) ? up[lane] : tp[lane - BAG];
    }
    const float4* emb4 = reinterpret_cast<const float4*>(emb);
    float4 accU = make_float4(0.f, 0.f, 0.f, 0.f);
    float4 accT = make_float4(0.f, 0.f, 0.f, 0.f);
#pragma unroll
    for (int i = 0; i < BAG; ++i) {
        const int iu = __shfl(myidx, i);
        const int it = __shfl(myidx, BAG + i);
        const float4 vu = emb4[(size_t)iu * (HIDDEN / 4) + lane];
        const float4 vt = emb4[(size_t)it * (HIDDEN / 4) + lane];
        accU.x += vu.x; accU.y += vu.y; accU.z += vu.z; accU.w += vu.w;
        accT.x += vt.x; accT.y += vt.y; accT.z += vt.z; accT.w += vt.w;
    }
    {
        float4* xv = reinterpret_cast<float4*>(&x_lds[wave][0]);
        xv[lane]      = accU;
        xv[64 + lane] = accT;
    }
    __syncthreads();
    {
        const int r    = tid >> 6;
        const int sub  = tid & 63;
        const int j    = sub >> 1;
        const int half = sub & 1;
        const float4* xr = reinterpret_cast<const float4*>(&x_lds[r][0]) + half * 64;
        const float4* wr = reinterpret_cast<const float4*>(w1 + (size_t)j * (2 * HIDDEN)) + half * 64;
        float s = 0.f;
#pragma unroll 8
        for (int k = 0; k < 64; ++k) {
            const float4 xk = xr[k];
            const float4 wk = wr[k];
            s += xk.x * wk.x + xk.y * wk.y + xk.z * wk.z + xk.w * wk.w;
        }
        s += __shfl_xor(s, 1);
        if (half == 0) { s += b1[j]; y1_lds[r][j] = fminf(fmaxf(s, 0.f), 1.f); }
    }
    __syncthreads();
    if (tid < 4 * 32) {
        const int r = tid >> 5;
        const int j = tid & 31;
        const float* wr = w2 + j * 32;
        float s = b2[j];
#pragma unroll
        for (int k = 0; k < 32; ++k) s += y1_lds[r][k] * wr[k];
        y2_lds[r][j] = fminf(fmaxf(s, 0.f), 1.f);
    }
    __syncthreads();
    if (tid < 4) {
        const int r = tid;
        float s = b3[0];
#pragma unroll
        for (int k = 0; k < 32; ++k) s += y2_lds[r][k] * w3[k];
        out[blockIdx.x * 4 + r] = tanhf(s);
    }
}

extern "C" void kernel_launch(void* const* d_in, const int* in_sizes, int n_in,
                              void* d_out, int out_size, void* d_ws, size_t ws_size,
                              hipStream_t stream) {
    const int*   us   = (const int*)  d_in[0];
    const int*   them = (const int*)  d_in[1];
    const float* emb  = (const float*)d_in[2];
    const float* w1   = (const float*)d_in[3];
    const float* b1   = (const float*)d_in[4];
    const float* w2   = (const float*)d_in[5];
    const float* b2   = (const float*)d_in[6];
    const float* w3   = (const float*)d_in[7];
    const float* b3   = (const float*)d_in[8];
    float* out = (float*)d_out;

    const int batch = in_sizes[0] / BAG;                       // 8192
    const size_t p_bytes  = (size_t)FEAT * NJ * sizeof(float); // 10.5 MB
    const size_t wf_bytes = 2048 * sizeof(int4);               // 32 KB

    if (ws_size >= p_bytes + wf_bytes) {
        float* P     = (float*)d_ws;
        int4*  Wfrag = (int4*)((char*)d_ws + p_bytes);
        k_pre_wfrag<<<1, 256, 0, stream>>>(w1, Wfrag);
        k0_project_mfma<<<NTILES, 256, 0, stream>>>(emb, Wfrag, P);
        k1_gather_mlp<<<batch / 4, 256, 0, stream>>>(us, them, P,
                                                     b1, w2, b2, w3, b3, out);
    } else {
        nnue_fused<<<(batch + 3) / 4, 256, 0, stream>>>(us, them, emb,
                                                        w1, b1, w2, b2, w3, b3, out);
    }
}